// Round 4
// baseline (2378.945 us; speedup 1.0000x reference)
//
#include <hip/hip_runtime.h>

#define NDIM  2048
#define WAVES 32
#define BCOLS 2176            // 0..2048 valid + pad
#define PADF  4096
#define PADB  4096
#define ENCB  0x40000000u
#define SENT  0xFFFFFFFFu

typedef unsigned long long u64;
typedef unsigned u32;

// Static scratch (not d_ws: harness poisons d_ws, never touches these).
__device__ __align__(16) float g_T[PADF + NDIM*NDIM*3 + PADB];     // exp(theta)
__device__ __align__(16) u64   g_B[(size_t)(WAVES+1) * BCOLS * 2]; // boundary handoff

struct __attribute__((aligned(4))) F4 { float x, y, z, w; };       // 4B-aligned vec load

__device__ __forceinline__ u64 ald(const u64* p) {
  return __hip_atomic_load(p, __ATOMIC_RELAXED, __HIP_MEMORY_SCOPE_AGENT);
}
__device__ __forceinline__ void ast(u64* p, u64 v) {
  __hip_atomic_store(p, v, __ATOMIC_RELAXED, __HIP_MEMORY_SCOPE_AGENT);
}
__device__ __forceinline__ float shup1(float x) {   // lane n <- lane n-1 (lane0 <- 0)
  int v = __builtin_amdgcn_update_dpp(0, __float_as_int(x), 0x138, 0xf, 0xf, false);
  return __int_as_float(v);
}

// ---------------- prep: exp(theta) + sentinel/boundary init ----------------
__global__ void vit_prep(const float* __restrict__ theta) {
  const int tid = blockIdx.x * blockDim.x + threadIdx.x;
  const int stride = gridDim.x * blockDim.x;
  const int n4 = (NDIM*NDIM*3) / 4;
  const float4* src = (const float4*)theta;
  float4* dst = (float4*)(g_T + PADF);
  for (int i = tid; i < n4; i += stride) {
    float4 v = src[i];
    float4 r;
    r.x = __expf(v.x); r.y = __expf(v.y); r.z = __expf(v.z); r.w = __expf(v.w);
    dst[i] = r;
  }
  const int nb = (WAVES+1) * BCOLS;
  const u64 hi0 = ((u64)ENCB) << 32;   // (Y=0, e=0)
  for (int i = tid; i < nb; i += stride) {
    int w = i / BCOLS;
    int c = i - w * BCOLS;
    u64 lo, hi;
    if (c > NDIM)    { lo = 0ull; hi = hi0; }
    else if (w == 0) { lo = (c == 0) ? (u64)__float_as_uint(1.0f) : 0ull; hi = hi0; }
    else if (c == 0) { lo = 0ull; hi = hi0; }
    else             { lo = ~0ull; hi = ~0ull; }          // sentinel
    ast(&g_B[(size_t)i*2],   lo);
    ast(&g_B[(size_t)i*2+1], hi);
  }
}

// ---------------- main: 32 waves, striped wavefront, exp-space -------------
__global__ void __launch_bounds__(64, 1) vit_main(const float* __restrict__ A,
                                                  float* __restrict__ out) {
  const int lane = threadIdx.x;
  const int w    = blockIdx.x;
  const bool isL0 = (lane == 0);

  const float a00 = __expf(A[0]), a01 = __expf(A[1]), a02 = __expf(A[2]);
  const float a10 = __expf(A[3]), a11 = __expf(A[4]), a12 = __expf(A[5]);
  const float a20 = __expf(A[6]), a21 = __expf(A[7]), a22 = __expf(A[8]);

  const float* tbase = g_T + PADF + (size_t)(w*64 + lane) * (NDIM*3);
  const u64* bin  = g_B + (size_t)w     * BCOLS * 2;
  u64*       bout = g_B + (size_t)(w+1) * BCOLS * 2;

  float Mp=0.f,Xp=0.f,Yp=0.f, Mu=0.f,Xu=0.f,Yu=0.f, Mud=0.f,Xud=0.f,Yud=0.f;
  int e_w = 0;

  float thA[48], thB[48];
  uint4 bndA, bndB;

  // batch loaders (explicit register double-buffer; pinned by sched_barrier at callsite)
  // RUN16(B) step u computes cell s=B+u+1 whose theta col is s-1-lane = B+u-lane,
  // so the batch for RUN16(B) must start at firstcol = B - lane.
  #define LDTH(th, firstcol) do {                                              \
    const F4* _p = (const F4*)(tbase + (firstcol)*3);                          \
    _Pragma("unroll")                                                          \
    for (int _q = 0; _q < 12; ++_q) {                                          \
      F4 _v = _p[_q];                                                          \
      (th)[4*_q]=_v.x; (th)[4*_q+1]=_v.y; (th)[4*_q+2]=_v.z; (th)[4*_q+3]=_v.w;\
    } } while (0)

  #define LDBND(dst, col0) do {                                                \
    int _c = (col0) + lane; if (_c > BCOLS-1) _c = BCOLS-1;                    \
    (dst) = *(const uint4*)(bin + (size_t)_c*2);                               \
  } while (0)

  #define RUN16(base, th, bnd) do {                                            \
    _Pragma("unroll")                                                          \
    for (int u = 0; u < 16; ++u) {                                             \
      const int s = (base) + u + 1;                                            \
      const float T0 = (th)[3*u], T1 = (th)[3*u+1], T2 = (th)[3*u+2];          \
      float mn = T0 * fmaf(a02, Yud, fmaf(a01, Xud, a00*Mud));                 \
      float xn = T1 * fmaf(a12, Yu,  fmaf(a11, Xu,  a10*Mu));                  \
      float yn = T2 * fmaf(a22, Yp,  fmaf(a21, Xp,  a20*Mp));                  \
      if (s >= 64 && lane == 63) {                                             \
        u64 lo = ((u64)__float_as_uint(xn) << 32) | __float_as_uint(mn);       \
        u64 hi = ((u64)(u32)(e_w + (int)ENCB) << 32) | __float_as_uint(yn);    \
        u64* bo = bout + (size_t)(s - 63)*2;                                   \
        ast(bo, lo); ast(bo + 1, hi);                                          \
      }                                                                        \
      if (s == 2111 && w == WAVES-1 && lane == 63)                             \
        out[0] = (log2f(mn + xn + yn) + (float)e_w) * 0.69314718055994531f;    \
      u32 mbu = (u32)__builtin_amdgcn_readlane((int)(bnd).x, u);               \
      u32 xbu = (u32)__builtin_amdgcn_readlane((int)(bnd).y, u);               \
      u32 ybu = (u32)__builtin_amdgcn_readlane((int)(bnd).z, u);               \
      u32 ebu = (u32)__builtin_amdgcn_readlane((int)(bnd).w, u);               \
      if (mbu == SENT || xbu == SENT || ybu == SENT || ebu == SENT) {          \
        const u64* pl = bin + (size_t)(s + 1)*2;                               \
        u64 lo, hi;                                                            \
        for (;;) {                                                             \
          lo = ald(pl); hi = ald(pl + 1);                                      \
          if ((u32)lo != SENT && (u32)(lo>>32) != SENT &&                      \
              (u32)hi != SENT && (u32)(hi>>32) != SENT) break;                 \
          __builtin_amdgcn_s_sleep(1);                                         \
        }                                                                      \
        mbu = (u32)lo; xbu = (u32)(lo>>32); ybu = (u32)hi; ebu = (u32)(hi>>32);\
      }                                                                        \
      int d = (int)(ebu - ENCB) - e_w;                                         \
      d = __builtin_amdgcn_readfirstlane(d);                                   \
      if (d > 48) {                                                            \
        const int ep = (int)(ebu - ENCB);                                      \
        const int sh = e_w - ep;                                               \
        mn = ldexpf(mn,sh); xn = ldexpf(xn,sh); yn = ldexpf(yn,sh);            \
        Mu = ldexpf(Mu,sh); Xu = ldexpf(Xu,sh); Yu = ldexpf(Yu,sh);            \
        e_w = ep; d = 0;                                                       \
      }                                                                        \
      Mud = Mu; Xud = Xu; Yud = Yu;                                            \
      const float sm = shup1(mn), sx = shup1(xn), sy = shup1(yn);              \
      Mu = isL0 ? ldexpf(__uint_as_float(mbu), d) : sm;                        \
      Xu = isL0 ? ldexpf(__uint_as_float(xbu), d) : sx;                        \
      Yu = isL0 ? ldexpf(__uint_as_float(ybu), d) : sy;                        \
      Mp = mn; Xp = xn; Yp = yn;                                               \
    } } while (0)

  #define RESCALE(base) do {                                                   \
    float m = fmaxf(fmaxf(Mp, Xp), Yp);                                        \
    const int jl = (base) + 16 - lane;                                         \
    if (jl < 1 || jl > NDIM) m = 0.0f;                                         \
    _Pragma("unroll")                                                          \
    for (int off = 1; off < 64; off <<= 1) m = fmaxf(m, __shfl_xor(m, off));   \
    int E = (int)((__float_as_uint(m) >> 23) & 0xFF) - 127;                    \
    if (m == 0.0f) E = 0;                                                      \
    const int sh = -E;                                                         \
    Mp = ldexpf(Mp,sh); Xp = ldexpf(Xp,sh); Yp = ldexpf(Yp,sh);                \
    Mu = ldexpf(Mu,sh); Xu = ldexpf(Xu,sh); Yu = ldexpf(Yu,sh);                \
    Mud= ldexpf(Mud,sh);Xud= ldexpf(Xud,sh);Yud= ldexpf(Yud,sh);               \
    e_w += E;                                                                  \
  } while (0)

  // initial batches for epoch 0 (RUN16(0) -> firstcol = 0 - lane)
  LDTH(thA, 0 - lane);
  LDBND(bndA, 2);
  __builtin_amdgcn_sched_barrier(0);

  // col 0 -> ud (prefilled, never sentinel)
  {
    u64 lo = ald(bin), hi = ald(bin + 1);
    if (isL0) {
      Mud = __uint_as_float((u32)lo);
      Xud = __uint_as_float((u32)(lo >> 32));
      Yud = __uint_as_float((u32)hi);
    }
  }
  // col 1 -> u (spin = pipeline fill)
  {
    u64 lo, hi;
    for (;;) {
      lo = ald(bin + 2); hi = ald(bin + 3);
      if ((u32)lo != SENT && (u32)(lo>>32) != SENT &&
          (u32)hi != SENT && (u32)(hi>>32) != SENT) break;
      __builtin_amdgcn_s_sleep(4);
    }
    int ep = (int)((u32)(hi >> 32) - ENCB);
    int dd = ep - e_w;
    dd = __builtin_amdgcn_readfirstlane(dd);
    if (dd > 48) { e_w = ep; dd = 0; }   // states are zero
    if (isL0) {
      Mu = ldexpf(__uint_as_float((u32)lo), dd);
      Xu = ldexpf(__uint_as_float((u32)(lo >> 32)), dd);
      Yu = ldexpf(__uint_as_float((u32)hi), dd);
    }
  }

  for (int base = 0; base < 2112; base += 32) {
    LDTH(thB, base + 16 - lane);        // for RUN16(base+16)
    LDBND(bndB, base + 18);
    __builtin_amdgcn_sched_barrier(0);
    RUN16(base, thA, bndA);
    RESCALE(base);

    LDTH(thA, base + 32 - lane);        // for RUN16(base+32)
    LDBND(bndA, base + 34);
    __builtin_amdgcn_sched_barrier(0);
    RUN16(base + 16, thB, bndB);
    RESCALE(base + 16);
  }
  #undef LDTH
  #undef LDBND
  #undef RUN16
  #undef RESCALE
}

extern "C" void kernel_launch(void* const* d_in, const int* in_sizes, int n_in,
                              void* d_out, int out_size, void* d_ws, size_t ws_size,
                              hipStream_t stream) {
  const float* theta = (const float*)d_in[0];
  const float* A     = (const float*)d_in[1];
  float* out = (float*)d_out;
  (void)in_sizes; (void)n_in; (void)out_size; (void)d_ws; (void)ws_size;
  vit_prep<<<dim3(4096), dim3(256), 0, stream>>>(theta);
  vit_main<<<dim3(WAVES), dim3(64), 0, stream>>>(A, out);
}